// Round 5
// baseline (1806.243 us; speedup 1.0000x reference)
//
#include <hip/hip_runtime.h>
#include <math.h>

namespace {
constexpr int kB = 256;
constexpr int kN = 1024;
constexpr int kC = 512;
constexpr int kNP1 = kN + 1;  // 1025 (visual rows + dustbin)
constexpr float kEPS = 1e-6f;
constexpr float kPOW = 0.9523809523809523f;    // ALPHA/(ALPHA+REG) = 1/1.05
constexpr float kSCALE = 28.8539008177792681f; // 20 * log2(e)

// ---- fast-path ws layout (bytes) ----
// vis8     : [0, 134,217,728)
// sim      : [+kB*kNP1*4)
// counters : [+kB*4)
constexpr size_t kVis8Bytes = (size_t)kB * kN * kC;
constexpr size_t kSimOffB = kVis8Bytes;
constexpr size_t kCntOffB = kSimOffB + (size_t)kB * kNP1 * sizeof(float);
constexpr size_t kWsNeeded = kCntOffB + (size_t)kB * sizeof(unsigned int);

// ---- fallback ws layout (floats) ----
constexpr size_t kFbSimOff = 0;
constexpr size_t kFbGammaOff = (size_t)kB * kNP1;
constexpr size_t kFbPartialOff = kFbGammaOff + (size_t)kB * kN;
constexpr int kNSplit = 4;
constexpr int kRowsPerSplit = kN / kNSplit;  // 256

typedef float f32x2 __attribute__((ext_vector_type(2)));
typedef float f32x4 __attribute__((ext_vector_type(4)));
}  // namespace

// ===========================================================================
// FUSED single kernel: 4096 blocks (16 per batch) x 1024 threads.
// Stage phase: each block computes sims + fp8 copy for 64 rows of its batch
//   (4 rows per wave -- round-2 granularity, regular cached loads).
// Terminal phase: the LAST block of each batch (atomic counter) runs the
//   round-2 K2 body: Sinkhorn in LDS + einsum over LLC-warm vis8 + outputs.
// Dispatch-order-safe: no spin waits; only "all 16 chunks done" dependency.
// ===========================================================================
__global__ __launch_bounds__(1024) void fused_uot_kernel(
    const float* __restrict__ prompt,       // [B, C]
    const float* __restrict__ vis,          // [B, N, C]
    const float* __restrict__ dustbin,      // [C]
    float* __restrict__ sim,                // [B, NP1]  (ws)
    unsigned char* __restrict__ vis8,       // [B, N, C] e4m3 (ws)
    unsigned int* __restrict__ counters,    // [B] zeroed per launch (ws)
    float* __restrict__ p_obs,              // [B, C]
    float* __restrict__ mass_out) {         // [B]
  const int b = blockIdx.x >> 4;
  const int chunk = blockIdx.x & 15;
  const int t = threadIdx.x;
  const int w = t >> 6;       // wave 0..15
  const int lane = t & 63;
  const int coff = lane * 8;  // lane owns channels [coff, coff+8)

  __shared__ float red[16];
  __shared__ float gs[kN];
  __shared__ float pacc[16][64][8];  // 32 KB einsum partials
  __shared__ int is_last;

  // ---------------- Stage phase: 4 rows per wave ----------------
  const float* prow = prompt + (size_t)b * kC;
  const f32x4 pa = *reinterpret_cast<const f32x4*>(prow + coff);
  const f32x4 pb = *reinterpret_cast<const f32x4*>(prow + coff + 4);
  float psq = pa.x * pa.x + pa.y * pa.y + pa.z * pa.z + pa.w * pa.w +
              pb.x * pb.x + pb.y * pb.y + pb.z * pb.z + pb.w * pb.w;
#pragma unroll
  for (int s = 1; s < 64; s <<= 1) psq += __shfl_xor(psq, s);
  const float pn = fmaxf(sqrtf(psq), 1e-12f);

  const int row0 = chunk * 64 + w * 4;
  const size_t base = ((size_t)b * kN + row0) * kC;
  const float* vptr = vis + base;
  unsigned char* v8ptr = vis8 + base;
  float* simw = sim + (size_t)b * kNP1 + row0;

#pragma unroll
  for (int r = 0; r < 4; ++r) {
    const float* vrow = vptr + (size_t)r * kC;
    const f32x4 va = *reinterpret_cast<const f32x4*>(vrow + coff);
    const f32x4 vb = *reinterpret_cast<const f32x4*>(vrow + coff + 4);

    float dot = va.x * pa.x + va.y * pa.y + va.z * pa.z + va.w * pa.w +
                vb.x * pb.x + vb.y * pb.y + vb.z * pb.z + vb.w * pb.w;
    float vsq = va.x * va.x + va.y * va.y + va.z * va.z + va.w * va.w +
                vb.x * vb.x + vb.y * vb.y + vb.z * vb.z + vb.w * vb.w;

    int pk0 = __builtin_amdgcn_cvt_pk_fp8_f32(va.x, va.y, 0, false);
    pk0 = __builtin_amdgcn_cvt_pk_fp8_f32(va.z, va.w, pk0, true);
    int pk1 = __builtin_amdgcn_cvt_pk_fp8_f32(vb.x, vb.y, 0, false);
    pk1 = __builtin_amdgcn_cvt_pk_fp8_f32(vb.z, vb.w, pk1, true);
    uint2 wv;
    wv.x = (unsigned)pk0;
    wv.y = (unsigned)pk1;
    *reinterpret_cast<uint2*>(v8ptr + (size_t)r * kC + coff) = wv;

#pragma unroll
    for (int s = 1; s < 64; s <<= 1) {
      dot += __shfl_xor(dot, s);
      vsq += __shfl_xor(vsq, s);
    }
    if (lane == 0) simw[r] = dot / (pn * fmaxf(sqrtf(vsq), 1e-12f));
  }

  // dustbin row: one wave per batch
  if (chunk == 15 && w == 15) {
    const f32x4 da = *reinterpret_cast<const f32x4*>(dustbin + coff);
    const f32x4 db = *reinterpret_cast<const f32x4*>(dustbin + coff + 4);
    float dot = da.x * pa.x + da.y * pa.y + da.z * pa.z + da.w * pa.w +
                db.x * pb.x + db.y * pb.y + db.z * pb.z + db.w * pb.w;
    float vsq = da.x * da.x + da.y * da.y + da.z * da.z + da.w * da.w +
                db.x * db.x + db.y * db.y + db.z * db.z + db.w * db.w;
#pragma unroll
    for (int s = 1; s < 64; s <<= 1) {
      dot += __shfl_xor(dot, s);
      vsq += __shfl_xor(vsq, s);
    }
    if (lane == 0)
      sim[(size_t)b * kNP1 + kN] = dot / (pn * fmaxf(sqrtf(vsq), 1e-12f));
  }

  // ---------------- chunk-completion handshake ----------------
  __syncthreads();  // drains all stores (vmcnt(0)) before the barrier
  if (t == 0) {
    __threadfence();  // release: make this block's sims/vis8 visible
    const unsigned old = atomicAdd(&counters[b], 1u);
    is_last = (old == 15u) ? 1 : 0;
  }
  __syncthreads();
  if (!is_last) return;
  __threadfence();  // acquire: see all 16 chunks' sims/vis8

  // ---------------- Terminal phase (round-2 K2 body) ----------------
  const float* simb = sim + (size_t)b * kNP1;
  const float K0 = exp2f((simb[t] - 1.0f) * kSCALE);
  const float Kd = (t == 0) ? exp2f((simb[kN] - 1.0f) * kSCALE) : 0.0f;
  float v0 = 1.0f, vd = 1.0f, u = 1.0f;

#pragma unroll
  for (int it = 0; it < 3; ++it) {
    float partial = K0 * v0 + Kd * vd;
#pragma unroll
    for (int s = 1; s < 64; s <<= 1) partial += __shfl_xor(partial, s);
    if (lane == 0) red[w] = partial;
    __syncthreads();
    float Kv = 0.f;
#pragma unroll
    for (int w2 = 0; w2 < 16; ++w2) Kv += red[w2];
    __syncthreads();
    u = exp2f(-kPOW * log2f(Kv + kEPS));
    v0 = exp2f(-kPOW * log2f(u * K0 + kEPS));
    vd = exp2f(-kPOW * log2f(u * Kd + kEPS));
  }

  const float g = u * K0 * v0;  // gamma for n = t (< N always)
  gs[t] = g;

  float pm = g;
#pragma unroll
  for (int s = 1; s < 64; s <<= 1) pm += __shfl_xor(pm, s);
  if (lane == 0) red[w] = pm;
  __syncthreads();  // publishes gs + red
  if (t == 0) {
    float m = 0.f;
#pragma unroll
    for (int w2 = 0; w2 < 16; ++w2) m += red[w2];
    mass_out[b] = m;
  }

  // einsum: p_obs[c] = sum_n gs[n] * vis8[b,n,c]; wave w handles n = w + 16k
  float acc[8] = {0.f, 0.f, 0.f, 0.f, 0.f, 0.f, 0.f, 0.f};
  const unsigned char* v8 = vis8 + (size_t)b * kN * kC + (size_t)coff;
#pragma unroll 8
  for (int k = 0; k < 64; ++k) {
    const int n = w + (k << 4);
    const float gn = gs[n];
    const uint2 wd = *reinterpret_cast<const uint2*>(v8 + (size_t)n * kC);
    const f32x2 f01 = __builtin_amdgcn_cvt_pk_f32_fp8(wd.x, false);
    const f32x2 f23 = __builtin_amdgcn_cvt_pk_f32_fp8(wd.x, true);
    const f32x2 f45 = __builtin_amdgcn_cvt_pk_f32_fp8(wd.y, false);
    const f32x2 f67 = __builtin_amdgcn_cvt_pk_f32_fp8(wd.y, true);
    acc[0] += gn * f01.x; acc[1] += gn * f01.y;
    acc[2] += gn * f23.x; acc[3] += gn * f23.y;
    acc[4] += gn * f45.x; acc[5] += gn * f45.y;
    acc[6] += gn * f67.x; acc[7] += gn * f67.y;
  }
#pragma unroll
  for (int j = 0; j < 8; ++j) pacc[w][lane][j] = acc[j];
  __syncthreads();
  if (t < 512) {
    float s = 0.f;
#pragma unroll
    for (int ss = 0; ss < 16; ++ss) s += pacc[ss][t >> 3][t & 7];
    p_obs[(size_t)b * kC + t] = s;
  }
}

// ===========================================================================
// FALLBACK (fp32 two-pass, round-1 proven; used only if ws too small)
// ===========================================================================
__global__ __launch_bounds__(256) void sim_kernel(
    const float* __restrict__ prompt, const float* __restrict__ vis,
    const float* __restrict__ dustbin, float* __restrict__ sim) {
  const int wid = threadIdx.x >> 6;
  const int lane = threadIdx.x & 63;
  const long long row = (long long)blockIdx.x * 4 + wid;
  if (row >= (long long)kB * kNP1) return;
  const int b = (int)(row / kNP1);
  const int n = (int)(row % kNP1);
  const float* vrow = (n < kN) ? (vis + ((size_t)b * kN + n) * kC) : dustbin;
  const float* prow = prompt + (size_t)b * kC;
  float dot = 0.f, vsq = 0.f, psq = 0.f;
#pragma unroll
  for (int h = 0; h < 2; ++h) {
    const int off = h * 256 + lane * 4;
    const float4 v4 = *reinterpret_cast<const float4*>(vrow + off);
    const float4 p4 = *reinterpret_cast<const float4*>(prow + off);
    dot += v4.x * p4.x + v4.y * p4.y + v4.z * p4.z + v4.w * p4.w;
    vsq += v4.x * v4.x + v4.y * v4.y + v4.z * v4.z + v4.w * v4.w;
    psq += p4.x * p4.x + p4.y * p4.y + p4.z * p4.z + p4.w * p4.w;
  }
#pragma unroll
  for (int s = 1; s < 64; s <<= 1) {
    dot += __shfl_xor(dot, s);
    vsq += __shfl_xor(vsq, s);
    psq += __shfl_xor(psq, s);
  }
  if (lane == 0) {
    const float pn = fmaxf(sqrtf(psq), 1e-12f);
    const float vn = fmaxf(sqrtf(vsq), 1e-12f);
    sim[row] = dot / (pn * vn);
  }
}

__global__ __launch_bounds__(1024) void sinkhorn_kernel(
    const float* __restrict__ sim, float* __restrict__ gamma,
    float* __restrict__ mass_out) {
  const int b = blockIdx.x;
  const int t = threadIdx.x;
  __shared__ float red[16];
  const float* simb = sim + (size_t)b * kNP1;
  const float K0 = exp2f((simb[t] - 1.0f) * kSCALE);
  const float K1 = (t == 0) ? exp2f((simb[kN] - 1.0f) * kSCALE) : 0.0f;
  float v0 = 1.0f, v1 = 1.0f, u = 1.0f;
  for (int it = 0; it < 3; ++it) {
    float partial = K0 * v0 + K1 * v1;
#pragma unroll
    for (int s = 1; s < 64; s <<= 1) partial += __shfl_xor(partial, s);
    if ((t & 63) == 0) red[t >> 6] = partial;
    __syncthreads();
    float Kv = 0.f;
#pragma unroll
    for (int w = 0; w < 16; ++w) Kv += red[w];
    __syncthreads();
    u = exp2f(-kPOW * log2f(Kv + kEPS));
    v0 = exp2f(-kPOW * log2f(u * K0 + kEPS));
    v1 = exp2f(-kPOW * log2f(u * K1 + kEPS));
  }
  const float g0 = u * K0 * v0;
  gamma[(size_t)b * kN + t] = g0;
  float partial = g0;
#pragma unroll
  for (int s = 1; s < 64; s <<= 1) partial += __shfl_xor(partial, s);
  if ((t & 63) == 0) red[t >> 6] = partial;
  __syncthreads();
  if (t == 0) {
    float m = 0.f;
#pragma unroll
    for (int w = 0; w < 16; ++w) m += red[w];
    mass_out[b] = m;
  }
}

__global__ __launch_bounds__(512) void pobs_kernel(
    const float* __restrict__ vis, const float* __restrict__ gamma,
    float* __restrict__ partial) {
  const int b = blockIdx.x / kNSplit;
  const int s = blockIdx.x % kNSplit;
  const int c = threadIdx.x;
  __shared__ float gsm[kRowsPerSplit];
  const float* g = gamma + (size_t)b * kN + (size_t)s * kRowsPerSplit;
  for (int i = threadIdx.x; i < kRowsPerSplit; i += 512) gsm[i] = g[i];
  __syncthreads();
  const float* vbase = vis + ((size_t)b * kN + (size_t)s * kRowsPerSplit) * kC;
  float acc = 0.f;
#pragma unroll 8
  for (int n = 0; n < kRowsPerSplit; ++n)
    acc += gsm[n] * vbase[(size_t)n * kC + c];
  partial[(size_t)blockIdx.x * kC + c] = acc;
}

__global__ __launch_bounds__(256) void reduce_kernel(
    const float* __restrict__ partial, float* __restrict__ p_obs) {
  const int i = blockIdx.x * 256 + threadIdx.x;
  if (i >= kB * kC) return;
  const int b = i / kC;
  const int c = i % kC;
  float s = 0.f;
#pragma unroll
  for (int k = 0; k < kNSplit; ++k)
    s += partial[((size_t)(b * kNSplit + k)) * kC + c];
  p_obs[i] = s;
}

// ===========================================================================

extern "C" void kernel_launch(void* const* d_in, const int* in_sizes, int n_in,
                              void* d_out, int out_size, void* d_ws,
                              size_t ws_size, hipStream_t stream) {
  const float* prompt = (const float*)d_in[0];
  const float* vis = (const float*)d_in[1];
  const float* dustbin = (const float*)d_in[2];
  float* out = (float*)d_out;  // p_obs [B*C] then total_mass [B]

  if (ws_size >= kWsNeeded) {
    unsigned char* ws8 = (unsigned char*)d_ws;
    unsigned char* vis8 = ws8;
    float* sim = (float*)(ws8 + kSimOffB);
    unsigned int* counters = (unsigned int*)(ws8 + kCntOffB);
    hipMemsetAsync(counters, 0, kB * sizeof(unsigned int), stream);
    fused_uot_kernel<<<kB * 16, 1024, 0, stream>>>(
        prompt, vis, dustbin, sim, vis8, counters, out,
        out + (size_t)kB * kC);
  } else {
    float* ws = (float*)d_ws;
    float* sim = ws + kFbSimOff;
    float* gamma = ws + kFbGammaOff;
    float* partial = ws + kFbPartialOff;
    const long long rows = (long long)kB * kNP1;
    sim_kernel<<<(int)((rows + 3) / 4), 256, 0, stream>>>(prompt, vis,
                                                          dustbin, sim);
    sinkhorn_kernel<<<kB, 1024, 0, stream>>>(sim, gamma, out + (size_t)kB * kC);
    pobs_kernel<<<kB * kNSplit, 512, 0, stream>>>(vis, gamma, partial);
    reduce_kernel<<<(kB * kC + 255) / 256, 256, 0, stream>>>(partial, out);
  }
}

// Round 7
// 150.039 us; speedup vs baseline: 12.0385x; 12.0385x over previous
//
#include <hip/hip_runtime.h>
#include <math.h>

namespace {
constexpr int kB = 256;
constexpr int kN = 1024;
constexpr int kC = 512;
constexpr int kNP1 = kN + 1;  // 1025 (visual rows + dustbin)
constexpr float kEPS = 1e-6f;
constexpr float kPOW = 0.9523809523809523f;  // ALPHA/(ALPHA+REG) = 1/1.05
constexpr float kLOG2E = 1.44269504088896341f;

// ---- fast-path ws layout (bytes) ----
// vis8 : [0, kB*kN*kC)                     134,217,728 B (e4m3 copy of vis)
// sim  : [kVis8Bytes, +kB*kNP1*4)            1,049,600 B
constexpr size_t kVis8Bytes = (size_t)kB * kN * kC;
constexpr size_t kSimOffB = kVis8Bytes;
constexpr size_t kWsNeeded = kVis8Bytes + (size_t)kB * kNP1 * sizeof(float);

// ---- fallback ws layout (floats) ----
constexpr size_t kFbSimOff = 0;
constexpr size_t kFbGammaOff = (size_t)kB * kNP1;
constexpr size_t kFbPartialOff = kFbGammaOff + (size_t)kB * kN;
constexpr int kNSplit = 4;
constexpr int kRowsPerSplit = kN / kNSplit;  // 256

typedef float f32x2 __attribute__((ext_vector_type(2)));
typedef float f32x4 __attribute__((ext_vector_type(4)));
}  // namespace

// ===========================================================================
// FAST PATH  (round-2 structure verbatim; ONLY change: nontemporal vis reads)
// ===========================================================================

// K1: sim[b,n] for all 1025 rows; also write e4m3 copy of vis (n < N).
// One wave per row, lane owns 8 contiguous channels [lane*8, lane*8+8).
// vis fp32 reads are read-once -> nontemporal (no-allocate), so the
// cacheable vis8 writes stay LLC-resident for K2's read-back.
__global__ __launch_bounds__(256) void sim_fp8_kernel(
    const float* __restrict__ prompt,       // [B, C]
    const float* __restrict__ vis,          // [B, N, C]
    const float* __restrict__ dustbin,      // [C]
    float* __restrict__ sim,                // [B, NP1]
    unsigned char* __restrict__ vis8) {     // [B, N, C] e4m3
  const int wid = threadIdx.x >> 6;
  const int lane = threadIdx.x & 63;
  const long long row = (long long)blockIdx.x * 4 + wid;
  if (row >= (long long)kB * kNP1) return;
  const int b = (int)(row / kNP1);
  const int n = (int)(row % kNP1);

  const float* vrow = (n < kN) ? (vis + ((size_t)b * kN + n) * kC) : dustbin;
  const float* prow = prompt + (size_t)b * kC;
  const int off = lane * 8;

  f32x4 va, vb;
  if (n < kN) {
    va = __builtin_nontemporal_load(
        reinterpret_cast<const f32x4*>(vrow + off));
    vb = __builtin_nontemporal_load(
        reinterpret_cast<const f32x4*>(vrow + off + 4));
  } else {
    va = *reinterpret_cast<const f32x4*>(vrow + off);
    vb = *reinterpret_cast<const f32x4*>(vrow + off + 4);
  }
  const f32x4 pa = *reinterpret_cast<const f32x4*>(prow + off);
  const f32x4 pb = *reinterpret_cast<const f32x4*>(prow + off + 4);

  float dot = va.x * pa.x + va.y * pa.y + va.z * pa.z + va.w * pa.w +
              vb.x * pb.x + vb.y * pb.y + vb.z * pb.z + vb.w * pb.w;
  float vsq = va.x * va.x + va.y * va.y + va.z * va.z + va.w * va.w +
              vb.x * vb.x + vb.y * vb.y + vb.z * vb.z + vb.w * vb.w;
  float psq = pa.x * pa.x + pa.y * pa.y + pa.z * pa.z + pa.w * pa.w +
              pb.x * pb.x + pb.y * pb.y + pb.z * pb.z + pb.w * pb.w;

  // e4m3 copy (only real visual rows)
  if (n < kN) {
    int pk0 = __builtin_amdgcn_cvt_pk_fp8_f32(va.x, va.y, 0, false);
    pk0 = __builtin_amdgcn_cvt_pk_fp8_f32(va.z, va.w, pk0, true);
    int pk1 = __builtin_amdgcn_cvt_pk_fp8_f32(vb.x, vb.y, 0, false);
    pk1 = __builtin_amdgcn_cvt_pk_fp8_f32(vb.z, vb.w, pk1, true);
    uint2 w;
    w.x = (unsigned)pk0;
    w.y = (unsigned)pk1;
    *reinterpret_cast<uint2*>(vis8 + ((size_t)b * kN + n) * kC + off) = w;
  }

#pragma unroll
  for (int s = 1; s < 64; s <<= 1) {
    dot += __shfl_xor(dot, s);
    vsq += __shfl_xor(vsq, s);
    psq += __shfl_xor(psq, s);
  }
  if (lane == 0) {
    const float pn = fmaxf(sqrtf(psq), 1e-12f);
    const float vn = fmaxf(sqrtf(vsq), 1e-12f);
    sim[row] = dot / (pn * vn);
  }
}

// K2: per-batch Sinkhorn + einsum + both outputs, one 1024-thread block per b.
__global__ __launch_bounds__(1024) void sinkhorn_pobs_kernel(
    const float* __restrict__ sim,          // [B, NP1]
    const unsigned char* __restrict__ vis8, // [B, N, C] e4m3
    float* __restrict__ p_obs,              // [B, C]
    float* __restrict__ mass_out) {         // [B]
  const int b = blockIdx.x;
  const int t = threadIdx.x;
  __shared__ float red[16];
  __shared__ float gs[kN];
  __shared__ float lds[16][64][8];  // 32 KB

  const float* simb = sim + (size_t)b * kNP1;
  const float K0 = exp2f((simb[t] - 1.0f) * (20.0f * kLOG2E));
  const float Kd = (t == 0) ? exp2f((simb[kN] - 1.0f) * (20.0f * kLOG2E)) : 0.0f;
  float v0 = 1.0f, vd = 1.0f, u = 1.0f;

#pragma unroll
  for (int it = 0; it < 3; ++it) {
    float partial = K0 * v0 + Kd * vd;
#pragma unroll
    for (int s = 1; s < 64; s <<= 1) partial += __shfl_xor(partial, s);
    if ((t & 63) == 0) red[t >> 6] = partial;
    __syncthreads();
    float Kv = 0.f;
#pragma unroll
    for (int w = 0; w < 16; ++w) Kv += red[w];
    __syncthreads();
    // x^-POW = exp2(-POW * log2(x)); x > 0 always
    u = exp2f(-kPOW * log2f(Kv + kEPS));
    v0 = exp2f(-kPOW * log2f(u * K0 + kEPS));
    vd = exp2f(-kPOW * log2f(u * Kd + kEPS));
  }

  const float g = u * K0 * v0;  // gamma for n = t (< N always)
  gs[t] = g;

  // total_mass over n < N
  float pm = g;
#pragma unroll
  for (int s = 1; s < 64; s <<= 1) pm += __shfl_xor(pm, s);
  if ((t & 63) == 0) red[t >> 6] = pm;
  __syncthreads();  // also publishes gs[]
  if (t == 0) {
    float m = 0.f;
#pragma unroll
    for (int w = 0; w < 16; ++w) m += red[w];
    mass_out[b] = m;
  }

  // einsum: p_obs[c] = sum_n gs[n] * vis8[b,n,c]
  const int sub = t >> 6;       // 0..15  (== wave id -> gs[n] is a broadcast)
  const int cq = t & 63;        // channel group: channels [8*cq, 8*cq+8)
  float acc[8] = {0.f, 0.f, 0.f, 0.f, 0.f, 0.f, 0.f, 0.f};
  const unsigned char* vbase = vis8 + (size_t)b * kN * kC + (size_t)cq * 8;
#pragma unroll 4
  for (int k = 0; k < 64; ++k) {
    const int n = sub + (k << 4);
    const float gn = gs[n];
    const uint2 w = *reinterpret_cast<const uint2*>(vbase + (size_t)n * kC);
    const f32x2 f01 = __builtin_amdgcn_cvt_pk_f32_fp8(w.x, false);
    const f32x2 f23 = __builtin_amdgcn_cvt_pk_f32_fp8(w.x, true);
    const f32x2 f45 = __builtin_amdgcn_cvt_pk_f32_fp8(w.y, false);
    const f32x2 f67 = __builtin_amdgcn_cvt_pk_f32_fp8(w.y, true);
    acc[0] += gn * f01.x; acc[1] += gn * f01.y;
    acc[2] += gn * f23.x; acc[3] += gn * f23.y;
    acc[4] += gn * f45.x; acc[5] += gn * f45.y;
    acc[6] += gn * f67.x; acc[7] += gn * f67.y;
  }
#pragma unroll
  for (int j = 0; j < 8; ++j) lds[sub][cq][j] = acc[j];
  __syncthreads();
  if (t < 512) {
    // channel c == t: cq = t>>3, j = t&7
    float s = 0.f;
#pragma unroll
    for (int ss = 0; ss < 16; ++ss) s += lds[ss][t >> 3][t & 7];
    p_obs[(size_t)b * kC + t] = s;
  }
}

// ===========================================================================
// FALLBACK PATH (round-1 fp32 two-pass; used only if ws too small)
// ===========================================================================

__global__ __launch_bounds__(256) void sim_kernel(
    const float* __restrict__ prompt, const float* __restrict__ vis,
    const float* __restrict__ dustbin, float* __restrict__ sim) {
  const int wid = threadIdx.x >> 6;
  const int lane = threadIdx.x & 63;
  const long long row = (long long)blockIdx.x * 4 + wid;
  if (row >= (long long)kB * kNP1) return;
  const int b = (int)(row / kNP1);
  const int n = (int)(row % kNP1);
  const float* vrow = (n < kN) ? (vis + ((size_t)b * kN + n) * kC) : dustbin;
  const float* prow = prompt + (size_t)b * kC;
  float dot = 0.f, vsq = 0.f, psq = 0.f;
#pragma unroll
  for (int h = 0; h < 2; ++h) {
    const int off = h * 256 + lane * 4;
    const float4 v4 = *reinterpret_cast<const float4*>(vrow + off);
    const float4 p4 = *reinterpret_cast<const float4*>(prow + off);
    dot += v4.x * p4.x + v4.y * p4.y + v4.z * p4.z + v4.w * p4.w;
    vsq += v4.x * v4.x + v4.y * v4.y + v4.z * v4.z + v4.w * v4.w;
    psq += p4.x * p4.x + p4.y * p4.y + p4.z * p4.z + p4.w * p4.w;
  }
#pragma unroll
  for (int s = 1; s < 64; s <<= 1) {
    dot += __shfl_xor(dot, s);
    vsq += __shfl_xor(vsq, s);
    psq += __shfl_xor(psq, s);
  }
  if (lane == 0) {
    const float pn = fmaxf(sqrtf(psq), 1e-12f);
    const float vn = fmaxf(sqrtf(vsq), 1e-12f);
    sim[row] = dot / (pn * vn);
  }
}

__global__ __launch_bounds__(1024) void sinkhorn_kernel(
    const float* __restrict__ sim, float* __restrict__ gamma,
    float* __restrict__ mass_out) {
  const int b = blockIdx.x;
  const int t = threadIdx.x;
  __shared__ float red[16];
  const float* simb = sim + (size_t)b * kNP1;
  const float K0 = exp2f((simb[t] - 1.0f) * (20.0f * kLOG2E));
  const float K1 = (t == 0) ? exp2f((simb[kN] - 1.0f) * (20.0f * kLOG2E)) : 0.0f;
  float v0 = 1.0f, v1 = 1.0f, u = 1.0f;
  for (int it = 0; it < 3; ++it) {
    float partial = K0 * v0 + K1 * v1;
#pragma unroll
    for (int s = 1; s < 64; s <<= 1) partial += __shfl_xor(partial, s);
    if ((t & 63) == 0) red[t >> 6] = partial;
    __syncthreads();
    float Kv = 0.f;
#pragma unroll
    for (int w = 0; w < 16; ++w) Kv += red[w];
    __syncthreads();
    u = exp2f(-kPOW * log2f(Kv + kEPS));
    v0 = exp2f(-kPOW * log2f(u * K0 + kEPS));
    v1 = exp2f(-kPOW * log2f(u * K1 + kEPS));
  }
  const float g0 = u * K0 * v0;
  gamma[(size_t)b * kN + t] = g0;
  float partial = g0;
#pragma unroll
  for (int s = 1; s < 64; s <<= 1) partial += __shfl_xor(partial, s);
  if ((t & 63) == 0) red[t >> 6] = partial;
  __syncthreads();
  if (t == 0) {
    float m = 0.f;
#pragma unroll
    for (int w = 0; w < 16; ++w) m += red[w];
    mass_out[b] = m;
  }
}

__global__ __launch_bounds__(512) void pobs_kernel(
    const float* __restrict__ vis, const float* __restrict__ gamma,
    float* __restrict__ partial) {
  const int b = blockIdx.x / kNSplit;
  const int s = blockIdx.x % kNSplit;
  const int c = threadIdx.x;
  __shared__ float gsm[kRowsPerSplit];
  const float* g = gamma + (size_t)b * kN + (size_t)s * kRowsPerSplit;
  for (int i = threadIdx.x; i < kRowsPerSplit; i += 512) gsm[i] = g[i];
  __syncthreads();
  const float* vbase = vis + ((size_t)b * kN + (size_t)s * kRowsPerSplit) * kC;
  float acc = 0.f;
#pragma unroll 8
  for (int n = 0; n < kRowsPerSplit; ++n)
    acc += gsm[n] * vbase[(size_t)n * kC + c];
  partial[(size_t)blockIdx.x * kC + c] = acc;
}

__global__ __launch_bounds__(256) void reduce_kernel(
    const float* __restrict__ partial, float* __restrict__ p_obs) {
  const int i = blockIdx.x * 256 + threadIdx.x;
  if (i >= kB * kC) return;
  const int b = i / kC;
  const int c = i % kC;
  float s = 0.f;
#pragma unroll
  for (int k = 0; k < kNSplit; ++k)
    s += partial[((size_t)(b * kNSplit + k)) * kC + c];
  p_obs[i] = s;
}

// ===========================================================================

extern "C" void kernel_launch(void* const* d_in, const int* in_sizes, int n_in,
                              void* d_out, int out_size, void* d_ws,
                              size_t ws_size, hipStream_t stream) {
  const float* prompt = (const float*)d_in[0];
  const float* vis = (const float*)d_in[1];
  const float* dustbin = (const float*)d_in[2];
  float* out = (float*)d_out;  // p_obs [B*C] then total_mass [B]

  if (ws_size >= kWsNeeded) {
    unsigned char* vis8 = (unsigned char*)d_ws;
    float* sim = (float*)((unsigned char*)d_ws + kSimOffB);
    const long long rows = (long long)kB * kNP1;
    sim_fp8_kernel<<<(int)((rows + 3) / 4), 256, 0, stream>>>(
        prompt, vis, dustbin, sim, vis8);
    sinkhorn_pobs_kernel<<<kB, 1024, 0, stream>>>(
        sim, vis8, out, out + (size_t)kB * kC);
  } else {
    float* ws = (float*)d_ws;
    float* sim = ws + kFbSimOff;
    float* gamma = ws + kFbGammaOff;
    float* partial = ws + kFbPartialOff;
    const long long rows = (long long)kB * kNP1;
    sim_kernel<<<(int)((rows + 3) / 4), 256, 0, stream>>>(prompt, vis,
                                                          dustbin, sim);
    sinkhorn_kernel<<<kB, 1024, 0, stream>>>(sim, gamma, out + (size_t)kB * kC);
    pobs_kernel<<<kB * kNSplit, 512, 0, stream>>>(sim, gamma, partial);
    reduce_kernel<<<(kB * kC + 255) / 256, 256, 0, stream>>>(partial, out);
  }
}